// Round 12
// baseline (769.446 us; speedup 1.0000x reference)
//
#include <hip/hip_runtime.h>
#include <math.h>

typedef __attribute__((ext_vector_type(8))) short short8;
typedef __attribute__((ext_vector_type(4))) float f32x4;
typedef unsigned short u16;

#define NT 4096      // tokens (B*S)
#define DM 1024      // d_model
#define DF 4096      // d_ff
#define NE 8         // experts
#define HROWS 9216   // max padded rows: 8192 + 8*128
#define TIT 72       // max m-tiles total
#define YROWS (2 * NT + 8)

static __device__ __forceinline__ u16 f2bf(float f) {
  union { float f; unsigned u; } v; v.f = f;
  return (u16)((v.u + 0x7fffu + ((v.u >> 16) & 1u)) >> 16);  // RNE
}

// branch-free tanh-form GELU: gelu(x) = x - x / (2^z + 1), z = k1*x + k2*x^3
static __device__ __forceinline__ float fast_gelu(float x) {
  float x2 = x * x;
  float z = x * __builtin_fmaf(x2, 0.1029392294f, 2.302118131f);
  float e, r;
  asm("v_exp_f32 %0, %1" : "=v"(e) : "v"(z));        // e = 2^z
  float e1 = e + 1.0f;
  asm("v_rcp_f32 %0, %1" : "=v"(r) : "v"(e1));       // r = 1/(e+1); e=inf -> 0
  return __builtin_fmaf(-x, r, x);
}

// chunked XCD swizzle: nwg % 8 == 0. consecutive vids land on one XCD.
static __device__ __forceinline__ int xcd_swz(int bid, int nwg) {
  int per = nwg >> 3;
  return (bid & 7) * per + (bid >> 3);
}

// ---------------- gating + x->bf16 convert: one wave per token ----------------
__global__ __launch_bounds__(256) void gate_k(const float* __restrict__ x,
                                              const float* __restrict__ Wg,
                                              int* __restrict__ te,
                                              float* __restrict__ tw,
                                              u16* __restrict__ xbf) {
  int t = blockIdx.x * 4 + (threadIdx.x >> 6);
  int l = threadIdx.x & 63;
  float a0=0,a1=0,a2=0,a3=0,a4=0,a5=0,a6=0,a7=0;
  const float* xr = x + (size_t)t * DM;
  for (int k = l; k < DM; k += 64) {
    float xv = xr[k];
    const float4* wp = (const float4*)(Wg + k * 8);
    float4 w0 = wp[0], w1 = wp[1];
    a0 += xv * w0.x; a1 += xv * w0.y; a2 += xv * w0.z; a3 += xv * w0.w;
    a4 += xv * w1.x; a5 += xv * w1.y; a6 += xv * w1.z; a7 += xv * w1.w;
  }
  u16* xo = xbf + (size_t)t * DM;
#pragma unroll
  for (int h = 0; h < 2; ++h) {
    int k = h * 512 + l * 8;
    float4 a = *(const float4*)(xr + k);
    float4 b = *(const float4*)(xr + k + 4);
    short8 o8 = { (short)f2bf(a.x), (short)f2bf(a.y), (short)f2bf(a.z), (short)f2bf(a.w),
                  (short)f2bf(b.x), (short)f2bf(b.y), (short)f2bf(b.z), (short)f2bf(b.w) };
    *(short8*)(xo + k) = o8;
  }
#pragma unroll
  for (int s = 32; s >= 1; s >>= 1) {
    a0 += __shfl_down(a0, s); a1 += __shfl_down(a1, s);
    a2 += __shfl_down(a2, s); a3 += __shfl_down(a3, s);
    a4 += __shfl_down(a4, s); a5 += __shfl_down(a5, s);
    a6 += __shfl_down(a6, s); a7 += __shfl_down(a7, s);
  }
  if (l == 0) {
    float lg[8] = {a0,a1,a2,a3,a4,a5,a6,a7};
    float m = lg[0];
#pragma unroll
    for (int e = 1; e < 8; ++e) m = fmaxf(m, lg[e]);
    float p[8], s = 0.f;
#pragma unroll
    for (int e = 0; e < 8; ++e) { p[e] = expf(lg[e] - m); s += p[e]; }
#pragma unroll
    for (int e = 0; e < 8; ++e) p[e] /= s;
    int i0 = 0; float v0 = p[0];
#pragma unroll
    for (int e = 1; e < 8; ++e) if (p[e] > v0) { v0 = p[e]; i0 = e; }
    int i1 = -1; float v1 = -1.f;
#pragma unroll
    for (int e = 0; e < 8; ++e) {
      if (e == i0) continue;
      if (p[e] > v1) { v1 = p[e]; i1 = e; }
    }
    float norm = v0 + v1 + 1e-8f;
    te[t*2]   = i0; te[t*2+1] = i1;
    tw[t*2]   = v0 / norm; tw[t*2+1] = v1 / norm;
  }
}

// ---------------- routing ----------------
__global__ __launch_bounds__(256) void route_k(const int* __restrict__ te,
                                               const float* __restrict__ tw,
                                               int* __restrict__ meta,
                                               int* __restrict__ lt,
                                               float* __restrict__ lw) {
  int i = blockIdx.x * 256 + threadIdx.x;
  if (i >= NT * 2) return;
  int e = te[i];
  float w = tw[i];
  int pos = atomicAdd(&meta[e], 1);
  lt[e * NT + pos] = i;        // fused token*2 + slot
  lw[e * NT + pos] = w;
}

// meta: [0:8) cnt | [8:16) padded cnt | [16:24) row base | [24] ntiles | [32..) tile table
__global__ __launch_bounds__(256) void finalize_k(int* __restrict__ meta,
                                                  int* __restrict__ lt,
                                                  float* __restrict__ lw) {
  __shared__ int s_cnt[8], s_pc[8];
  if (threadIdx.x == 0) {
    int base = 0, nt_ = 0;
    for (int e = 0; e < 8; ++e) {
      int c = meta[e];
      int pc = (c + 127) & ~127;
      s_cnt[e] = c; s_pc[e] = pc;
      meta[8 + e] = pc;
      meta[16 + e] = base;
      base += pc;
      for (int mt = 0; mt < pc / 128; ++mt) meta[32 + nt_++] = (e << 16) | mt;
    }
    meta[24] = nt_;
  }
  __syncthreads();
  for (int e = 0; e < 8; ++e) {
    int c = s_cnt[e], pc = s_pc[e];
    for (int i = c + (int)threadIdx.x; i < pc; i += 256) {
      lt[e * NT + i] = 2 * NT;   // dummy -> trash Y row; ffn1 clamps gather
      lw[e * NT + i] = 0.f;
    }
  }
}

// ---------------- prepass body: one 64x64 tile  [K][N] fp32 -> [N][K] bf16 ----------------
static __device__ __forceinline__ void prep_tile(const float* __restrict__ ie,
                                                 u16* __restrict__ oe,
                                                 int K, int N, int k0, int n0) {
  __shared__ u16 t[64 * 72];
  const int tid = threadIdx.x;
  const int kr = tid >> 4, nq = (tid & 15) * 4;
#pragma unroll
  for (int it = 0; it < 4; ++it) {
    int k = it * 16 + kr;
    float4 v = *(const float4*)(ie + (size_t)(k0 + k) * N + n0 + nq);
    t[(nq + 0) * 72 + k] = f2bf(v.x);
    t[(nq + 1) * 72 + k] = f2bf(v.y);
    t[(nq + 2) * 72 + k] = f2bf(v.z);
    t[(nq + 3) * 72 + k] = f2bf(v.w);
  }
  __syncthreads();
#pragma unroll
  for (int it = 0; it < 2; ++it) {
    int idx = it * 256 + tid;
    int n = idx >> 3, kc = idx & 7;
    short8 v = *(const short8*)&t[n * 72 + kc * 8];
    *(short8*)(oe + (size_t)(n0 + n) * K + k0 + kc * 8) = v;
  }
}

// standalone (fallback path): W [E][K][N] fp32 -> [E][N][K] bf16
__global__ __launch_bounds__(256) void prep_wT(const float* __restrict__ in,
                                               u16* __restrict__ out, int K, int N) {
  const int e = blockIdx.z;
  prep_tile(in + (size_t)e * K * N, out + (size_t)e * K * N,
            K, N, blockIdx.y * 64, blockIdx.x * 64);
}

// merged: W1 and W2 in one launch (8192 + 8192 tile-blocks)
__global__ __launch_bounds__(256) void prep_both(const float* __restrict__ W1,
                                                 const float* __restrict__ W2,
                                                 u16* __restrict__ W1T,
                                                 u16* __restrict__ W2T) {
  int bid = blockIdx.x;
  if (bid < 8192) {
    int e = bid >> 10, rem = bid & 1023;           // 64 ntiles x 16 ktiles
    prep_tile(W1 + (size_t)e * DM * DF, W1T + (size_t)e * DM * DF,
              DM, DF, (rem >> 6) * 64, (rem & 63) * 64);
  } else {
    bid -= 8192;
    int e = bid >> 10, rem = bid & 1023;           // 16 ntiles x 64 ktiles
    prep_tile(W2 + (size_t)e * DF * DM, W2T + (size_t)e * DF * DM,
              DF, DM, (rem >> 4) * 64, (rem & 15) * 64);
  }
}

// ---------------- FFN1: direct global->fragment, no LDS, no barriers ----------------
__global__ __launch_bounds__(256) void ffn1_k(const u16* __restrict__ xbf,
                                              const u16* __restrict__ W1T,
                                              const float* __restrict__ b1,
                                              const int* __restrict__ lt,
                                              const int* __restrict__ meta,
                                              u16* __restrict__ H) {
  const int vid = xcd_swz(blockIdx.x, (DF / 128) * TIT);
  const int nt = vid & 31;            // DF/128
  const int ti = vid >> 5;            // tile-table index
  if (ti >= meta[24]) return;
  const int em = meta[32 + ti];
  const int e = em >> 16, mt = em & 0xffff;
  const int rbase = meta[16 + e];

  const int tid = threadIdx.x, lane = tid & 63, wv = tid >> 6;
  const int wm = wv >> 1, wn = wv & 1, l15 = lane & 15, l4 = lane >> 4;

  // per-lane fragment base pointers (k-chunk l4*8 elems; advance 32 elems/step)
  const u16* pa[4]; const u16* pb[4];
#pragma unroll
  for (int i = 0; i < 4; ++i) {
    int ra = wm * 64 + i * 16 + l15;
    int tok = lt[e * NT + mt * 128 + ra] >> 1; if (tok >= NT) tok = 0;
    pa[i] = xbf + (size_t)tok * DM + l4 * 8;
    int rb = wn * 64 + i * 16 + l15;
    pb[i] = W1T + ((size_t)e * DF + nt * 128 + rb) * DM + l4 * 8;
  }

  f32x4 acc[4][4];
#pragma unroll
  for (int mi = 0; mi < 4; ++mi)
#pragma unroll
    for (int ni = 0; ni < 4; ++ni) acc[mi][ni] = 0.f;

  const int NK = DM / 32;
#pragma unroll 8
  for (int ks = 0; ks < NK; ++ks) {
    short8 af[4], bf_[4];
#pragma unroll
    for (int i = 0; i < 4; ++i) {
      af[i]  = *(const short8*)pa[i];
      bf_[i] = *(const short8*)pb[i];
    }
#pragma unroll
    for (int mi = 0; mi < 4; ++mi)
#pragma unroll
      for (int ni = 0; ni < 4; ++ni)
        acc[mi][ni] = __builtin_amdgcn_mfma_f32_16x16x32_bf16(af[mi], bf_[ni], acc[mi][ni], 0, 0, 0);
#pragma unroll
    for (int i = 0; i < 4; ++i) { pa[i] += 32; pb[i] += 32; }
  }

  const size_t hrow0 = (size_t)rbase + mt * 128;
#pragma unroll
  for (int mi = 0; mi < 4; ++mi) {
#pragma unroll
    for (int ni = 0; ni < 4; ++ni) {
      int gn = nt * 128 + wn * 64 + ni * 16 + l15;
      float bias = b1[e * DF + gn];
      int rr = wm * 64 + mi * 16 + l4 * 4;
#pragma unroll
      for (int j = 0; j < 4; ++j) {
        float v = fast_gelu(acc[mi][ni][j] + bias);
        H[(hrow0 + rr + j) * DF + gn] = f2bf(v);
      }
    }
  }
}

// ---------------- FFN2: direct global->fragment, no LDS; per-slot Y or atomic ----------------
template <bool USEY>
__global__ __launch_bounds__(256) void ffn2_k(const u16* __restrict__ H,
                                              const u16* __restrict__ W2T,
                                              const float* __restrict__ b2,
                                              const int* __restrict__ lt,
                                              const float* __restrict__ lw,
                                              const int* __restrict__ meta,
                                              float* __restrict__ Y,
                                              float* __restrict__ out) {
  const int vid = xcd_swz(blockIdx.x, (DM / 128) * TIT);
  const int nt = vid & 7;             // DM/128
  const int ti = vid >> 3;
  if (ti >= meta[24]) return;
  const int em = meta[32 + ti];
  const int e = em >> 16, mt = em & 0xffff;
  const int rbase = meta[16 + e];

  const int tid = threadIdx.x, lane = tid & 63, wv = tid >> 6;
  const int wm = wv >> 1, wn = wv & 1, l15 = lane & 15, l4 = lane >> 4;

  const u16* pa[4]; const u16* pb[4];
#pragma unroll
  for (int i = 0; i < 4; ++i) {
    int ra = wm * 64 + i * 16 + l15;
    pa[i] = H + ((size_t)rbase + mt * 128 + ra) * DF + l4 * 8;
    int rb = wn * 64 + i * 16 + l15;
    pb[i] = W2T + ((size_t)e * DM + nt * 128 + rb) * DF + l4 * 8;
  }

  f32x4 acc[4][4];
#pragma unroll
  for (int mi = 0; mi < 4; ++mi)
#pragma unroll
    for (int ni = 0; ni < 4; ++ni) acc[mi][ni] = 0.f;

  const int NK = DF / 32;
#pragma unroll 8
  for (int ks = 0; ks < NK; ++ks) {
    short8 af[4], bf_[4];
#pragma unroll
    for (int i = 0; i < 4; ++i) {
      af[i]  = *(const short8*)pa[i];
      bf_[i] = *(const short8*)pb[i];
    }
#pragma unroll
    for (int mi = 0; mi < 4; ++mi)
#pragma unroll
      for (int ni = 0; ni < 4; ++ni)
        acc[mi][ni] = __builtin_amdgcn_mfma_f32_16x16x32_bf16(af[mi], bf_[ni], acc[mi][ni], 0, 0, 0);
#pragma unroll
    for (int i = 0; i < 4; ++i) { pa[i] += 32; pb[i] += 32; }
  }

  const int lbase = e * NT + mt * 128;
#pragma unroll
  for (int mi = 0; mi < 4; ++mi) {
    int rr = wm * 64 + mi * 16 + l4 * 4;
#pragma unroll
    for (int j = 0; j < 4; ++j) {
      int r = rr + j;
      int ts = lt[lbase + r];
      float w = lw[lbase + r];
#pragma unroll
      for (int ni = 0; ni < 4; ++ni) {
        int gn = nt * 128 + wn * 64 + ni * 16 + l15;
        float v = w * (acc[mi][ni][j] + b2[e * DM + gn]);
        if (USEY) {
          Y[(size_t)ts * DM + gn] = v;
        } else {
          int tok = ts >> 1;
          if (tok >= NT) tok = 0;
          atomicAdd(out + (size_t)tok * DM + gn, v);
        }
      }
    }
  }
}

// ---------------- combine: out[t] = Y[2t] + Y[2t+1] ----------------
__global__ __launch_bounds__(256) void combine_k(const float* __restrict__ Y,
                                                 float* __restrict__ out) {
  size_t i4 = (size_t)blockIdx.x * 256 + threadIdx.x;
  size_t t = i4 >> 8;
  int c4 = (int)(i4 & 255) * 4;
  const float4 a = *(const float4*)(Y + (2 * t) * DM + c4);
  const float4 b = *(const float4*)(Y + (2 * t + 1) * DM + c4);
  float4 o = { a.x + b.x, a.y + b.y, a.z + b.z, a.w + b.w };
  *(float4*)(out + t * DM + c4) = o;
}

extern "C" void kernel_launch(void* const* d_in, const int* in_sizes, int n_in,
                              void* d_out, int out_size, void* d_ws, size_t ws_size,
                              hipStream_t stream) {
  const float* x  = (const float*)d_in[0];
  const float* Wg = (const float*)d_in[1];
  const float* W1 = (const float*)d_in[2];
  const float* b1 = (const float*)d_in[3];
  const float* W2 = (const float*)d_in[4];
  const float* b2 = (const float*)d_in[5];
  float* out = (float*)d_out;

  char* ws = (char*)d_ws;
  size_t o = 0;
  auto take = [&](size_t sz) { size_t p = o; o = (o + sz + 1023) & ~(size_t)1023; return p; };

  int*   meta = (int*)(ws + take(1024));
  int*   te   = (int*)(ws + take((size_t)NT * 2 * 4));
  float* tw   = (float*)(ws + take((size_t)NT * 2 * 4));
  int*   lt   = (int*)(ws + take((size_t)NE * NT * 4));
  float* lw   = (float*)(ws + take((size_t)NE * NT * 4));
  u16*   xbf  = (u16*)(ws + take((size_t)NT * DM * 2));
  u16*   W1T  = (u16*)(ws + take((size_t)NE * DM * DF * 2));
  u16*   H    = (u16*)(ws + take((size_t)HROWS * DF * 2));
  size_t needB = o;
  size_t ySz = (size_t)YROWS * DM * 4;
  size_t needA = needB + ((size_t)NE * DM * DF * 2 + 1024) + (ySz + 1024);

  bool pathA = (ws_size >= needA);
  u16*   W2T;
  float* Y = nullptr;
  if (pathA) {
    W2T = (u16*)(ws + take((size_t)NE * DM * DF * 2));
    Y   = (float*)(ws + take(ySz));
  } else {
    W2T = W1T;   // alias: converted between ffn1 and ffn2
  }

  hipMemsetAsync(meta, 0, 1024, stream);
  if (!pathA) hipMemsetAsync(out, 0, (size_t)NT * DM * 4, stream);

  gate_k<<<NT / 4, 256, 0, stream>>>(x, Wg, te, tw, xbf);
  route_k<<<(NT * 2) / 256, 256, 0, stream>>>(te, tw, meta, lt, lw);
  finalize_k<<<1, 256, 0, stream>>>(meta, lt, lw);

  if (pathA) {
    prep_both<<<16384, 256, 0, stream>>>(W1, W2, W1T, W2T);
  } else {
    prep_wT<<<dim3(DF / 64, DM / 64, NE), 256, 0, stream>>>(W1, W1T, DM, DF);
  }

  ffn1_k<<<(DF / 128) * TIT, 256, 0, stream>>>(xbf, W1T, b1, lt, meta, H);

  if (!pathA)
    prep_wT<<<dim3(DM / 64, DF / 64, NE), 256, 0, stream>>>(W2, W2T, DF, DM);

  if (pathA) {
    ffn2_k<true><<<(DM / 128) * TIT, 256, 0, stream>>>(H, W2T, b2, lt, lw, meta, Y, out);
    combine_k<<<NT, 256, 0, stream>>>(Y, out);
  } else {
    ffn2_k<false><<<(DM / 128) * TIT, 256, 0, stream>>>(H, W2T, b2, lt, lw, meta, Y, out);
  }
}

// Round 13
// 387.359 us; speedup vs baseline: 1.9864x; 1.9864x over previous
//
#include <hip/hip_runtime.h>
#include <math.h>

typedef __attribute__((ext_vector_type(8))) short short8;
typedef __attribute__((ext_vector_type(4))) float f32x4;
typedef unsigned short u16;

#define NT 4096      // tokens (B*S)
#define DM 1024      // d_model
#define DF 4096      // d_ff
#define NE 8         // experts
#define HROWS 9216   // max padded rows: 8192 + 8*128
#define TIT 72       // max m-tiles total
#define YROWS (2 * NT + 8)

static __device__ __forceinline__ u16 f2bf(float f) {
  union { float f; unsigned u; } v; v.f = f;
  return (u16)((v.u + 0x7fffu + ((v.u >> 16) & 1u)) >> 16);  // RNE
}

// branch-free tanh-form GELU: gelu(x) = x - x / (2^z + 1), z = k1*x + k2*x^3
static __device__ __forceinline__ float fast_gelu(float x) {
  float x2 = x * x;
  float z = x * __builtin_fmaf(x2, 0.1029392294f, 2.302118131f);
  float e, r;
  asm("v_exp_f32 %0, %1" : "=v"(e) : "v"(z));        // e = 2^z
  float e1 = e + 1.0f;
  asm("v_rcp_f32 %0, %1" : "=v"(r) : "v"(e1));       // r = 1/(e+1); e=inf -> 0
  return __builtin_fmaf(-x, r, x);
}

static __device__ __forceinline__ void gload16(const void* g, void* l) {
  __builtin_amdgcn_global_load_lds((const __attribute__((address_space(1))) void*)g,
                                   (__attribute__((address_space(3))) void*)l, 16, 0, 0);
}

// chunked XCD swizzle: nwg % 8 == 0. consecutive vids land on one XCD.
static __device__ __forceinline__ int xcd_swz(int bid, int nwg) {
  int per = nwg >> 3;
  return (bid & 7) * per + (bid >> 3);
}

// ---------------- gating + x->bf16 convert: one wave per token ----------------
__global__ __launch_bounds__(256) void gate_k(const float* __restrict__ x,
                                              const float* __restrict__ Wg,
                                              int* __restrict__ te,
                                              float* __restrict__ tw,
                                              u16* __restrict__ xbf) {
  int t = blockIdx.x * 4 + (threadIdx.x >> 6);
  int l = threadIdx.x & 63;
  float a0=0,a1=0,a2=0,a3=0,a4=0,a5=0,a6=0,a7=0;
  const float* xr = x + (size_t)t * DM;
  for (int k = l; k < DM; k += 64) {
    float xv = xr[k];
    const float4* wp = (const float4*)(Wg + k * 8);
    float4 w0 = wp[0], w1 = wp[1];
    a0 += xv * w0.x; a1 += xv * w0.y; a2 += xv * w0.z; a3 += xv * w0.w;
    a4 += xv * w1.x; a5 += xv * w1.y; a6 += xv * w1.z; a7 += xv * w1.w;
  }
  u16* xo = xbf + (size_t)t * DM;
#pragma unroll
  for (int h = 0; h < 2; ++h) {
    int k = h * 512 + l * 8;
    float4 a = *(const float4*)(xr + k);
    float4 b = *(const float4*)(xr + k + 4);
    short8 o8 = { (short)f2bf(a.x), (short)f2bf(a.y), (short)f2bf(a.z), (short)f2bf(a.w),
                  (short)f2bf(b.x), (short)f2bf(b.y), (short)f2bf(b.z), (short)f2bf(b.w) };
    *(short8*)(xo + k) = o8;
  }
#pragma unroll
  for (int s = 32; s >= 1; s >>= 1) {
    a0 += __shfl_down(a0, s); a1 += __shfl_down(a1, s);
    a2 += __shfl_down(a2, s); a3 += __shfl_down(a3, s);
    a4 += __shfl_down(a4, s); a5 += __shfl_down(a5, s);
    a6 += __shfl_down(a6, s); a7 += __shfl_down(a7, s);
  }
  if (l == 0) {
    float lg[8] = {a0,a1,a2,a3,a4,a5,a6,a7};
    float m = lg[0];
#pragma unroll
    for (int e = 1; e < 8; ++e) m = fmaxf(m, lg[e]);
    float p[8], s = 0.f;
#pragma unroll
    for (int e = 0; e < 8; ++e) { p[e] = expf(lg[e] - m); s += p[e]; }
#pragma unroll
    for (int e = 0; e < 8; ++e) p[e] /= s;
    int i0 = 0; float v0 = p[0];
#pragma unroll
    for (int e = 1; e < 8; ++e) if (p[e] > v0) { v0 = p[e]; i0 = e; }
    int i1 = -1; float v1 = -1.f;
#pragma unroll
    for (int e = 0; e < 8; ++e) {
      if (e == i0) continue;
      if (p[e] > v1) { v1 = p[e]; i1 = e; }
    }
    float norm = v0 + v1 + 1e-8f;
    te[t*2]   = i0; te[t*2+1] = i1;
    tw[t*2]   = v0 / norm; tw[t*2+1] = v1 / norm;
  }
}

// ---------------- routing ----------------
__global__ __launch_bounds__(256) void route_k(const int* __restrict__ te,
                                               const float* __restrict__ tw,
                                               int* __restrict__ meta,
                                               int* __restrict__ lt,
                                               float* __restrict__ lw) {
  int i = blockIdx.x * 256 + threadIdx.x;
  if (i >= NT * 2) return;
  int e = te[i];
  float w = tw[i];
  int pos = atomicAdd(&meta[e], 1);
  lt[e * NT + pos] = i;        // fused token*2 + slot
  lw[e * NT + pos] = w;
}

// meta: [0:8) cnt | [8:16) padded cnt | [16:24) row base | [24] ntiles | [32..) tile table
__global__ __launch_bounds__(256) void finalize_k(int* __restrict__ meta,
                                                  int* __restrict__ lt,
                                                  float* __restrict__ lw) {
  __shared__ int s_cnt[8], s_pc[8];
  if (threadIdx.x == 0) {
    int base = 0, nt_ = 0;
    for (int e = 0; e < 8; ++e) {
      int c = meta[e];
      int pc = (c + 127) & ~127;
      s_cnt[e] = c; s_pc[e] = pc;
      meta[8 + e] = pc;
      meta[16 + e] = base;
      base += pc;
      for (int mt = 0; mt < pc / 128; ++mt) meta[32 + nt_++] = (e << 16) | mt;
    }
    meta[24] = nt_;
  }
  __syncthreads();
  for (int e = 0; e < 8; ++e) {
    int c = s_cnt[e], pc = s_pc[e];
    for (int i = c + (int)threadIdx.x; i < pc; i += 256) {
      lt[e * NT + i] = 2 * NT;   // dummy -> trash Y row; ffn1 clamps gather
      lw[e * NT + i] = 0.f;
    }
  }
}

// ---------------- prepass body: one 64x64 tile  [K][N] fp32 -> [N][K] bf16 ----------------
static __device__ __forceinline__ void prep_tile(const float* __restrict__ ie,
                                                 u16* __restrict__ oe,
                                                 int K, int N, int k0, int n0) {
  __shared__ u16 t[64 * 72];
  const int tid = threadIdx.x;
  const int kr = tid >> 4, nq = (tid & 15) * 4;
#pragma unroll
  for (int it = 0; it < 4; ++it) {
    int k = it * 16 + kr;
    float4 v = *(const float4*)(ie + (size_t)(k0 + k) * N + n0 + nq);
    t[(nq + 0) * 72 + k] = f2bf(v.x);
    t[(nq + 1) * 72 + k] = f2bf(v.y);
    t[(nq + 2) * 72 + k] = f2bf(v.z);
    t[(nq + 3) * 72 + k] = f2bf(v.w);
  }
  __syncthreads();
#pragma unroll
  for (int it = 0; it < 2; ++it) {
    int idx = it * 256 + tid;
    int n = idx >> 3, kc = idx & 7;
    short8 v = *(const short8*)&t[n * 72 + kc * 8];
    *(short8*)(oe + (size_t)(n0 + n) * K + k0 + kc * 8) = v;
  }
}

// standalone (fallback path): W [E][K][N] fp32 -> [E][N][K] bf16
__global__ __launch_bounds__(256) void prep_wT(const float* __restrict__ in,
                                               u16* __restrict__ out, int K, int N) {
  const int e = blockIdx.z;
  prep_tile(in + (size_t)e * K * N, out + (size_t)e * K * N,
            K, N, blockIdx.y * 64, blockIdx.x * 64);
}

// merged: W1 and W2 in one launch (8192 + 8192 tile-blocks)
__global__ __launch_bounds__(256) void prep_both(const float* __restrict__ W1,
                                                 const float* __restrict__ W2,
                                                 u16* __restrict__ W1T,
                                                 u16* __restrict__ W2T) {
  int bid = blockIdx.x;
  if (bid < 8192) {
    int e = bid >> 10, rem = bid & 1023;           // 64 ntiles x 16 ktiles
    prep_tile(W1 + (size_t)e * DM * DF, W1T + (size_t)e * DM * DF,
              DM, DF, (rem >> 6) * 64, (rem & 63) * 64);
  } else {
    bid -= 8192;
    int e = bid >> 10, rem = bid & 1023;           // 16 ntiles x 64 ktiles
    prep_tile(W2 + (size_t)e * DF * DM, W2T + (size_t)e * DF * DM,
              DF, DM, (rem >> 4) * 64, (rem & 15) * 64);
  }
}

// ---------------- FFN1: 128M x 256N, 512 threads, shared A-tile ----------------
__global__ __launch_bounds__(512) void ffn1_k(const u16* __restrict__ xbf,
                                              const u16* __restrict__ W1T,
                                              const float* __restrict__ b1,
                                              const int* __restrict__ lt,
                                              const int* __restrict__ meta,
                                              u16* __restrict__ H) {
  const int vid = xcd_swz(blockIdx.x, (DF / 256) * TIT);
  const int nt = vid & 15;            // DF/256
  const int ti = vid >> 4;            // tile-table index
  if (ti >= meta[24]) return;
  const int em = meta[32 + ti];
  const int e = em >> 16, mt = em & 0xffff;
  const int rbase = meta[16 + e];

  __shared__ u16 As[128 * 32];        // 8 KB
  __shared__ u16 Bs[256 * 32];        // 16 KB

  const int tid = threadIdx.x, lane = tid & 63, wv = tid >> 6;
  const int wg = wv >> 2, wq = wv & 3;
  const int wm = wq >> 1, wn = wq & 1, l15 = lane & 15, l4 = lane >> 4;

  // A staging: 1 gload/thread (128 rows x 4 chunks = 512 slots)
  int r0 = tid >> 2, s0 = tid & 3;
  int kg0 = s0 ^ ((r0 >> 1) & 3);
  int tok0 = lt[e * NT + mt * 128 + r0] >> 1; if (tok0 >= NT) tok0 = 0;
  const u16* pa0 = xbf + (size_t)tok0 * DM + kg0 * 8;
  // B staging: 2 gloads/thread (256 rows x 4 chunks = 1024 slots)
  const u16* pb[2];
#pragma unroll
  for (int it = 0; it < 2; ++it) {
    int idx = it * 512 + tid;
    int r = idx >> 2;
    int kg = (idx & 3) ^ ((r >> 1) & 3);
    pb[it] = W1T + ((size_t)e * DF + nt * 256 + r) * DM + kg * 8;
  }
  u16* ldsA = As + (size_t)(wv * 64) * 8;
  u16* ldsB0 = Bs + (size_t)(wv * 64) * 8;
  u16* ldsB1 = Bs + (size_t)(512 + wv * 64) * 8;

  int aoff[4], boff[4];
#pragma unroll
  for (int i = 0; i < 4; ++i) {
    int ra = wm * 64 + i * 16 + l15;
    aoff[i] = ra * 32 + (l4 ^ ((ra >> 1) & 3)) * 8;
    int rb = wg * 128 + wn * 64 + i * 16 + l15;
    boff[i] = rb * 32 + (l4 ^ ((rb >> 1) & 3)) * 8;
  }

  f32x4 acc[4][4];
#pragma unroll
  for (int mi = 0; mi < 4; ++mi)
#pragma unroll
    for (int ni = 0; ni < 4; ++ni) acc[mi][ni] = 0.f;

  const int NK = DM / 32;
  for (int ks = 0; ks < NK; ++ks) {
    __syncthreads();
    gload16(pa0, ldsA);
    gload16(pb[0], ldsB0);
    gload16(pb[1], ldsB1);
    pa0 += 32; pb[0] += 32; pb[1] += 32;
    __syncthreads();

    short8 af[4], bf_[4];
#pragma unroll
    for (int i = 0; i < 4; ++i) {
      af[i]  = *(const short8*)&As[aoff[i]];
      bf_[i] = *(const short8*)&Bs[boff[i]];
    }
#pragma unroll
    for (int mi = 0; mi < 4; ++mi)
#pragma unroll
      for (int ni = 0; ni < 4; ++ni)
        acc[mi][ni] = __builtin_amdgcn_mfma_f32_16x16x32_bf16(af[mi], bf_[ni], acc[mi][ni], 0, 0, 0);
  }

  const size_t hrow0 = (size_t)rbase + mt * 128;
#pragma unroll
  for (int mi = 0; mi < 4; ++mi) {
#pragma unroll
    for (int ni = 0; ni < 4; ++ni) {
      int gn = nt * 256 + wg * 128 + wn * 64 + ni * 16 + l15;
      float bias = b1[e * DF + gn];
      int rr = wm * 64 + mi * 16 + l4 * 4;
#pragma unroll
      for (int j = 0; j < 4; ++j) {
        float v = fast_gelu(acc[mi][ni][j] + bias);
        H[(hrow0 + rr + j) * DF + gn] = f2bf(v);
      }
    }
  }
}

// ---------------- FFN2: 128M x 256N, 512 threads, shared A-tile ----------------
template <bool USEY>
__global__ __launch_bounds__(512) void ffn2_k(const u16* __restrict__ H,
                                              const u16* __restrict__ W2T,
                                              const float* __restrict__ b2,
                                              const int* __restrict__ lt,
                                              const float* __restrict__ lw,
                                              const int* __restrict__ meta,
                                              float* __restrict__ Y,
                                              float* __restrict__ out) {
  const int vid = xcd_swz(blockIdx.x, (DM / 256) * TIT);
  const int nt = vid & 3;             // DM/256
  const int ti = vid >> 2;
  if (ti >= meta[24]) return;
  const int em = meta[32 + ti];
  const int e = em >> 16, mt = em & 0xffff;
  const int rbase = meta[16 + e];

  __shared__ u16 As[128 * 32];
  __shared__ u16 Bs[256 * 32];
  __shared__ int s_ts[128];
  __shared__ float s_w[128];

  const int tid = threadIdx.x, lane = tid & 63, wv = tid >> 6;
  const int wg = wv >> 2, wq = wv & 3;
  const int wm = wq >> 1, wn = wq & 1, l15 = lane & 15, l4 = lane >> 4;

  if (tid < 128) {
    s_ts[tid] = lt[e * NT + mt * 128 + tid];
    s_w[tid]  = lw[e * NT + mt * 128 + tid];
  }

  int r0 = tid >> 2, s0 = tid & 3;
  int kg0 = s0 ^ ((r0 >> 1) & 3);
  const u16* pa0 = H + ((size_t)rbase + mt * 128 + r0) * DF + kg0 * 8;
  const u16* pb[2];
#pragma unroll
  for (int it = 0; it < 2; ++it) {
    int idx = it * 512 + tid;
    int r = idx >> 2;
    int kg = (idx & 3) ^ ((r >> 1) & 3);
    pb[it] = W2T + ((size_t)e * DM + nt * 256 + r) * DF + kg * 8;
  }
  u16* ldsA = As + (size_t)(wv * 64) * 8;
  u16* ldsB0 = Bs + (size_t)(wv * 64) * 8;
  u16* ldsB1 = Bs + (size_t)(512 + wv * 64) * 8;

  int aoff[4], boff[4];
#pragma unroll
  for (int i = 0; i < 4; ++i) {
    int ra = wm * 64 + i * 16 + l15;
    aoff[i] = ra * 32 + (l4 ^ ((ra >> 1) & 3)) * 8;
    int rb = wg * 128 + wn * 64 + i * 16 + l15;
    boff[i] = rb * 32 + (l4 ^ ((rb >> 1) & 3)) * 8;
  }

  f32x4 acc[4][4];
#pragma unroll
  for (int mi = 0; mi < 4; ++mi)
#pragma unroll
    for (int ni = 0; ni < 4; ++ni) acc[mi][ni] = 0.f;

  const int NK = DF / 32;
  for (int ks = 0; ks < NK; ++ks) {
    __syncthreads();
    gload16(pa0, ldsA);
    gload16(pb[0], ldsB0);
    gload16(pb[1], ldsB1);
    pa0 += 32; pb[0] += 32; pb[1] += 32;
    __syncthreads();

    short8 af[4], bf_[4];
#pragma unroll
    for (int i = 0; i < 4; ++i) {
      af[i]  = *(const short8*)&As[aoff[i]];
      bf_[i] = *(const short8*)&Bs[boff[i]];
    }
#pragma unroll
    for (int mi = 0; mi < 4; ++mi)
#pragma unroll
      for (int ni = 0; ni < 4; ++ni)
        acc[mi][ni] = __builtin_amdgcn_mfma_f32_16x16x32_bf16(af[mi], bf_[ni], acc[mi][ni], 0, 0, 0);
  }

#pragma unroll
  for (int mi = 0; mi < 4; ++mi) {
#pragma unroll
    for (int ni = 0; ni < 4; ++ni) {
      int gn = nt * 256 + wg * 128 + wn * 64 + ni * 16 + l15;
      float bias = b2[e * DM + gn];
      int rr = wm * 64 + mi * 16 + l4 * 4;
#pragma unroll
      for (int j = 0; j < 4; ++j) {
        int r = rr + j;
        float w = s_w[r];
        int ts = s_ts[r];
        float v = w * (acc[mi][ni][j] + bias);
        if (USEY) {
          Y[(size_t)ts * DM + gn] = v;
        } else {
          int tok = ts >> 1;
          if (tok >= NT) tok = 0;
          atomicAdd(out + (size_t)tok * DM + gn, v);
        }
      }
    }
  }
}

// ---------------- combine: out[t] = Y[2t] + Y[2t+1] ----------------
__global__ __launch_bounds__(256) void combine_k(const float* __restrict__ Y,
                                                 float* __restrict__ out) {
  size_t i4 = (size_t)blockIdx.x * 256 + threadIdx.x;
  size_t t = i4 >> 8;
  int c4 = (int)(i4 & 255) * 4;
  const float4 a = *(const float4*)(Y + (2 * t) * DM + c4);
  const float4 b = *(const float4*)(Y + (2 * t + 1) * DM + c4);
  float4 o = { a.x + b.x, a.y + b.y, a.z + b.z, a.w + b.w };
  *(float4*)(out + t * DM + c4) = o;
}

extern "C" void kernel_launch(void* const* d_in, const int* in_sizes, int n_in,
                              void* d_out, int out_size, void* d_ws, size_t ws_size,
                              hipStream_t stream) {
  const float* x  = (const float*)d_in[0];
  const float* Wg = (const float*)d_in[1];
  const float* W1 = (const float*)d_in[2];
  const float* b1 = (const float*)d_in[3];
  const float* W2 = (const float*)d_in[4];
  const float* b2 = (const float*)d_in[5];
  float* out = (float*)d_out;

  char* ws = (char*)d_ws;
  size_t o = 0;
  auto take = [&](size_t sz) { size_t p = o; o = (o + sz + 1023) & ~(size_t)1023; return p; };

  int*   meta = (int*)(ws + take(1024));
  int*   te   = (int*)(ws + take((size_t)NT * 2 * 4));
  float* tw   = (float*)(ws + take((size_t)NT * 2 * 4));
  int*   lt   = (int*)(ws + take((size_t)NE * NT * 4));
  float* lw   = (float*)(ws + take((size_t)NE * NT * 4));
  u16*   xbf  = (u16*)(ws + take((size_t)NT * DM * 2));
  u16*   W1T  = (u16*)(ws + take((size_t)NE * DM * DF * 2));
  u16*   H    = (u16*)(ws + take((size_t)HROWS * DF * 2));
  size_t needB = o;
  size_t ySz = (size_t)YROWS * DM * 4;
  size_t needA = needB + ((size_t)NE * DM * DF * 2 + 1024) + (ySz + 1024);

  bool pathA = (ws_size >= needA);
  u16*   W2T;
  float* Y = nullptr;
  if (pathA) {
    W2T = (u16*)(ws + take((size_t)NE * DM * DF * 2));
    Y   = (float*)(ws + take(ySz));
  } else {
    W2T = W1T;   // alias: converted between ffn1 and ffn2
  }

  hipMemsetAsync(meta, 0, 1024, stream);
  if (!pathA) hipMemsetAsync(out, 0, (size_t)NT * DM * 4, stream);

  gate_k<<<NT / 4, 256, 0, stream>>>(x, Wg, te, tw, xbf);
  route_k<<<(NT * 2) / 256, 256, 0, stream>>>(te, tw, meta, lt, lw);
  finalize_k<<<1, 256, 0, stream>>>(meta, lt, lw);

  if (pathA) {
    prep_both<<<16384, 256, 0, stream>>>(W1, W2, W1T, W2T);
  } else {
    prep_wT<<<dim3(DF / 64, DM / 64, NE), 256, 0, stream>>>(W1, W1T, DM, DF);
  }

  ffn1_k<<<(DF / 256) * TIT, 512, 0, stream>>>(xbf, W1T, b1, lt, meta, H);

  if (!pathA)
    prep_wT<<<dim3(DM / 64, DF / 64, NE), 256, 0, stream>>>(W2, W2T, DF, DM);

  if (pathA) {
    ffn2_k<true><<<(DM / 256) * TIT, 512, 0, stream>>>(H, W2T, b2, lt, lw, meta, Y, out);
    combine_k<<<NT, 256, 0, stream>>>(Y, out);
  } else {
    ffn2_k<false><<<(DM / 256) * TIT, 512, 0, stream>>>(H, W2T, b2, lt, lw, meta, Y, out);
  }
}

// Round 14
// 379.052 us; speedup vs baseline: 2.0299x; 1.0219x over previous
//
#include <hip/hip_runtime.h>
#include <math.h>

typedef __attribute__((ext_vector_type(8))) short short8;
typedef __attribute__((ext_vector_type(4))) float f32x4;
typedef unsigned short u16;

#define NT 4096      // tokens (B*S)
#define DM 1024      // d_model
#define DF 4096      // d_ff
#define NE 8         // experts
#define HROWS 9216   // max padded rows: 8192 + 8*128
#define TIT 72       // max m-tiles total

static __device__ __forceinline__ u16 f2bf(float f) {
  union { float f; unsigned u; } v; v.f = f;
  return (u16)((v.u + 0x7fffu + ((v.u >> 16) & 1u)) >> 16);  // RNE
}

// branch-free tanh-form GELU: gelu(x) = x - x / (2^z + 1), z = k1*x + k2*x^3
static __device__ __forceinline__ float fast_gelu(float x) {
  float x2 = x * x;
  float z = x * __builtin_fmaf(x2, 0.1029392294f, 2.302118131f);
  float e, r;
  asm("v_exp_f32 %0, %1" : "=v"(e) : "v"(z));        // e = 2^z
  float e1 = e + 1.0f;
  asm("v_rcp_f32 %0, %1" : "=v"(r) : "v"(e1));       // r = 1/(e+1); e=inf -> 0
  return __builtin_fmaf(-x, r, x);
}

static __device__ __forceinline__ void gload16(const void* g, void* l) {
  __builtin_amdgcn_global_load_lds((const __attribute__((address_space(1))) void*)g,
                                   (__attribute__((address_space(3))) void*)l, 16, 0, 0);
}

// chunked XCD swizzle: nwg % 8 == 0. consecutive vids land on one XCD.
static __device__ __forceinline__ int xcd_swz(int bid, int nwg) {
  int per = nwg >> 3;
  return (bid & 7) * per + (bid >> 3);
}

// ---------------- gating + x->bf16 convert: one wave per token ----------------
__global__ __launch_bounds__(256) void gate_k(const float* __restrict__ x,
                                              const float* __restrict__ Wg,
                                              int* __restrict__ te,
                                              float* __restrict__ tw,
                                              u16* __restrict__ xbf) {
  int t = blockIdx.x * 4 + (threadIdx.x >> 6);
  int l = threadIdx.x & 63;
  float a0=0,a1=0,a2=0,a3=0,a4=0,a5=0,a6=0,a7=0;
  const float* xr = x + (size_t)t * DM;
  for (int k = l; k < DM; k += 64) {
    float xv = xr[k];
    const float4* wp = (const float4*)(Wg + k * 8);
    float4 w0 = wp[0], w1 = wp[1];
    a0 += xv * w0.x; a1 += xv * w0.y; a2 += xv * w0.z; a3 += xv * w0.w;
    a4 += xv * w1.x; a5 += xv * w1.y; a6 += xv * w1.z; a7 += xv * w1.w;
  }
  u16* xo = xbf + (size_t)t * DM;
#pragma unroll
  for (int h = 0; h < 2; ++h) {
    int k = h * 512 + l * 8;
    float4 a = *(const float4*)(xr + k);
    float4 b = *(const float4*)(xr + k + 4);
    short8 o8 = { (short)f2bf(a.x), (short)f2bf(a.y), (short)f2bf(a.z), (short)f2bf(a.w),
                  (short)f2bf(b.x), (short)f2bf(b.y), (short)f2bf(b.z), (short)f2bf(b.w) };
    *(short8*)(xo + k) = o8;
  }
#pragma unroll
  for (int s = 32; s >= 1; s >>= 1) {
    a0 += __shfl_down(a0, s); a1 += __shfl_down(a1, s);
    a2 += __shfl_down(a2, s); a3 += __shfl_down(a3, s);
    a4 += __shfl_down(a4, s); a5 += __shfl_down(a5, s);
    a6 += __shfl_down(a6, s); a7 += __shfl_down(a7, s);
  }
  if (l == 0) {
    float lg[8] = {a0,a1,a2,a3,a4,a5,a6,a7};
    float m = lg[0];
#pragma unroll
    for (int e = 1; e < 8; ++e) m = fmaxf(m, lg[e]);
    float p[8], s = 0.f;
#pragma unroll
    for (int e = 0; e < 8; ++e) { p[e] = expf(lg[e] - m); s += p[e]; }
#pragma unroll
    for (int e = 0; e < 8; ++e) p[e] /= s;
    int i0 = 0; float v0 = p[0];
#pragma unroll
    for (int e = 1; e < 8; ++e) if (p[e] > v0) { v0 = p[e]; i0 = e; }
    int i1 = -1; float v1 = -1.f;
#pragma unroll
    for (int e = 0; e < 8; ++e) {
      if (e == i0) continue;
      if (p[e] > v1) { v1 = p[e]; i1 = e; }
    }
    float norm = v0 + v1 + 1e-8f;
    te[t*2]   = i0; te[t*2+1] = i1;
    tw[t*2]   = v0 / norm; tw[t*2+1] = v1 / norm;
  }
}

// ---------------- routing ----------------
__global__ __launch_bounds__(256) void route_k(const int* __restrict__ te,
                                               const float* __restrict__ tw,
                                               int* __restrict__ meta,
                                               int* __restrict__ lt,
                                               float* __restrict__ lw) {
  int i = blockIdx.x * 256 + threadIdx.x;
  if (i >= NT * 2) return;
  int e = te[i];
  float w = tw[i];
  int pos = atomicAdd(&meta[e], 1);
  lt[e * NT + pos] = i >> 1;   // token id
  lw[e * NT + pos] = w;
}

// meta: [0:8) cnt | [8:16) padded cnt | [16:24) row base | [24] ntiles | [32..) tile table
__global__ __launch_bounds__(256) void finalize_k(int* __restrict__ meta,
                                                  int* __restrict__ lt,
                                                  float* __restrict__ lw) {
  __shared__ int s_cnt[8], s_pc[8];
  if (threadIdx.x == 0) {
    int base = 0, nt_ = 0;
    for (int e = 0; e < 8; ++e) {
      int c = meta[e];
      int pc = (c + 127) & ~127;
      s_cnt[e] = c; s_pc[e] = pc;
      meta[8 + e] = pc;
      meta[16 + e] = base;
      base += pc;
      for (int mt = 0; mt < pc / 128; ++mt) meta[32 + nt_++] = (e << 16) | mt;
    }
    meta[24] = nt_;
  }
  __syncthreads();
  for (int e = 0; e < 8; ++e) {
    int c = s_cnt[e], pc = s_pc[e];
    for (int i = c + (int)threadIdx.x; i < pc; i += 256) {
      lt[e * NT + i] = NT;     // dummy token -> clamped gather, w=0
      lw[e * NT + i] = 0.f;
    }
  }
}

// ---------------- prepass body: one 64x64 tile  [K][N] fp32 -> [N][K] bf16 ----------------
static __device__ __forceinline__ void prep_tile(const float* __restrict__ ie,
                                                 u16* __restrict__ oe,
                                                 int K, int N, int k0, int n0) {
  __shared__ u16 t[64 * 72];
  const int tid = threadIdx.x;
  const int kr = tid >> 4, nq = (tid & 15) * 4;
#pragma unroll
  for (int it = 0; it < 4; ++it) {
    int k = it * 16 + kr;
    float4 v = *(const float4*)(ie + (size_t)(k0 + k) * N + n0 + nq);
    t[(nq + 0) * 72 + k] = f2bf(v.x);
    t[(nq + 1) * 72 + k] = f2bf(v.y);
    t[(nq + 2) * 72 + k] = f2bf(v.z);
    t[(nq + 3) * 72 + k] = f2bf(v.w);
  }
  __syncthreads();
#pragma unroll
  for (int it = 0; it < 2; ++it) {
    int idx = it * 256 + tid;
    int n = idx >> 3, kc = idx & 7;
    short8 v = *(const short8*)&t[n * 72 + kc * 8];
    *(short8*)(oe + (size_t)(n0 + n) * K + k0 + kc * 8) = v;
  }
}

// standalone (fallback path): W [E][K][N] fp32 -> [E][N][K] bf16
__global__ __launch_bounds__(256) void prep_wT(const float* __restrict__ in,
                                               u16* __restrict__ out, int K, int N) {
  const int e = blockIdx.z;
  prep_tile(in + (size_t)e * K * N, out + (size_t)e * K * N,
            K, N, blockIdx.y * 64, blockIdx.x * 64);
}

// merged: W1 and W2 in one launch (8192 + 8192 tile-blocks)
__global__ __launch_bounds__(256) void prep_both(const float* __restrict__ W1,
                                                 const float* __restrict__ W2,
                                                 u16* __restrict__ W1T,
                                                 u16* __restrict__ W2T) {
  int bid = blockIdx.x;
  if (bid < 8192) {
    int e = bid >> 10, rem = bid & 1023;           // 64 ntiles x 16 ktiles
    prep_tile(W1 + (size_t)e * DM * DF, W1T + (size_t)e * DM * DF,
              DM, DF, (rem >> 6) * 64, (rem & 63) * 64);
  } else {
    bid -= 8192;
    int e = bid >> 10, rem = bid & 1023;           // 16 ntiles x 64 ktiles
    prep_tile(W2 + (size_t)e * DF * DM, W2T + (size_t)e * DF * DM,
              DF, DM, (rem >> 4) * 64, (rem & 15) * 64);
  }
}

// ---------------- FFN1: H = gelu(Xg @ W1 + b1), R11 loop ----------------
__global__ __launch_bounds__(256) void ffn1_k(const u16* __restrict__ xbf,
                                              const u16* __restrict__ W1T,
                                              const float* __restrict__ b1,
                                              const int* __restrict__ lt,
                                              const int* __restrict__ meta,
                                              u16* __restrict__ H) {
  const int vid = xcd_swz(blockIdx.x, (DF / 128) * TIT);
  const int nt = vid & 31;            // DF/128
  const int ti = vid >> 5;            // tile-table index
  if (ti >= meta[24]) return;
  const int em = meta[32 + ti];
  const int e = em >> 16, mt = em & 0xffff;
  const int rbase = meta[16 + e];

  __shared__ u16 As[128 * 32];
  __shared__ u16 Bs[128 * 32];

  const int tid = threadIdx.x, lane = tid & 63, wv = tid >> 6;
  const int wm = wv >> 1, wn = wv & 1, l15 = lane & 15, l4 = lane >> 4;

  int r0i = tid >> 2, s0 = tid & 3;
  int r1i = (256 + tid) >> 2;
  int kg0 = s0 ^ ((r0i >> 1) & 3);
  int kg1 = s0 ^ ((r1i >> 1) & 3);
  int tok0 = lt[e * NT + mt * 128 + r0i]; if (tok0 >= NT) tok0 = 0;
  int tok1 = lt[e * NT + mt * 128 + r1i]; if (tok1 >= NT) tok1 = 0;
  const u16* pa0 = xbf + (size_t)tok0 * DM + kg0 * 8;
  const u16* pa1 = xbf + (size_t)tok1 * DM + kg1 * 8;
  const u16* pb0 = W1T + ((size_t)e * DF + nt * 128 + r0i) * DM + kg0 * 8;
  const u16* pb1 = W1T + ((size_t)e * DF + nt * 128 + r1i) * DM + kg1 * 8;
  const int lda0 = (wv * 64) * 8, lda1 = (256 + wv * 64) * 8;

  int aoff[4], boff[4];
#pragma unroll
  for (int i = 0; i < 4; ++i) {
    int ra = wm * 64 + i * 16 + l15;
    aoff[i] = ra * 32 + (l4 ^ ((ra >> 1) & 3)) * 8;
    int rb = wn * 64 + i * 16 + l15;
    boff[i] = rb * 32 + (l4 ^ ((rb >> 1) & 3)) * 8;
  }

  f32x4 acc[4][4];
#pragma unroll
  for (int mi = 0; mi < 4; ++mi)
#pragma unroll
    for (int ni = 0; ni < 4; ++ni) acc[mi][ni] = 0.f;

  const int NK = DM / 32;
  for (int ks = 0; ks < NK; ++ks) {
    __syncthreads();
    gload16(pa0, As + lda0); gload16(pa1, As + lda1);
    gload16(pb0, Bs + lda0); gload16(pb1, Bs + lda1);
    pa0 += 32; pa1 += 32; pb0 += 32; pb1 += 32;
    __syncthreads();

    short8 af[4], bf_[4];
#pragma unroll
    for (int i = 0; i < 4; ++i) {
      af[i]  = *(const short8*)&As[aoff[i]];
      bf_[i] = *(const short8*)&Bs[boff[i]];
    }
#pragma unroll
    for (int mi = 0; mi < 4; ++mi)
#pragma unroll
      for (int ni = 0; ni < 4; ++ni)
        acc[mi][ni] = __builtin_amdgcn_mfma_f32_16x16x32_bf16(af[mi], bf_[ni], acc[mi][ni], 0, 0, 0);
  }

  const size_t hrow0 = (size_t)rbase + mt * 128;
#pragma unroll
  for (int mi = 0; mi < 4; ++mi) {
#pragma unroll
    for (int ni = 0; ni < 4; ++ni) {
      int gn = nt * 128 + wn * 64 + ni * 16 + l15;
      float bias = b1[e * DF + gn];
      int rr = wm * 64 + mi * 16 + l4 * 4;
#pragma unroll
      for (int j = 0; j < 4; ++j) {
        float v = fast_gelu(acc[mi][ni][j] + bias);
        H[(hrow0 + rr + j) * DF + gn] = f2bf(v);
      }
    }
  }
}

// ---------------- FFN2: R11 loop; direct atomic scatter to out ----------------
__global__ __launch_bounds__(256) void ffn2_k(const u16* __restrict__ H,
                                              const u16* __restrict__ W2T,
                                              const float* __restrict__ b2,
                                              const int* __restrict__ lt,
                                              const float* __restrict__ lw,
                                              const int* __restrict__ meta,
                                              float* __restrict__ out) {
  const int vid = xcd_swz(blockIdx.x, (DM / 128) * TIT);
  const int nt = vid & 7;             // DM/128
  const int ti = vid >> 3;
  if (ti >= meta[24]) return;
  const int em = meta[32 + ti];
  const int e = em >> 16, mt = em & 0xffff;
  const int rbase = meta[16 + e];

  __shared__ u16 As[128 * 32];
  __shared__ u16 Bs[128 * 32];
  __shared__ int s_ts[128];
  __shared__ float s_w[128];

  const int tid = threadIdx.x, lane = tid & 63, wv = tid >> 6;
  const int wm = wv >> 1, wn = wv & 1, l15 = lane & 15, l4 = lane >> 4;

  if (tid < 128) {
    s_ts[tid] = lt[e * NT + mt * 128 + tid];
    s_w[tid]  = lw[e * NT + mt * 128 + tid];
  }

  int r0i = tid >> 2, s0 = tid & 3;
  int r1i = (256 + tid) >> 2;
  int kg0 = s0 ^ ((r0i >> 1) & 3);
  int kg1 = s0 ^ ((r1i >> 1) & 3);
  const u16* pa0 = H + ((size_t)rbase + mt * 128 + r0i) * DF + kg0 * 8;
  const u16* pa1 = H + ((size_t)rbase + mt * 128 + r1i) * DF + kg1 * 8;
  const u16* pb0 = W2T + ((size_t)e * DM + nt * 128 + r0i) * DF + kg0 * 8;
  const u16* pb1 = W2T + ((size_t)e * DM + nt * 128 + r1i) * DF + kg1 * 8;
  const int lda0 = (wv * 64) * 8, lda1 = (256 + wv * 64) * 8;

  int aoff[4], boff[4];
#pragma unroll
  for (int i = 0; i < 4; ++i) {
    int ra = wm * 64 + i * 16 + l15;
    aoff[i] = ra * 32 + (l4 ^ ((ra >> 1) & 3)) * 8;
    int rb = wn * 64 + i * 16 + l15;
    boff[i] = rb * 32 + (l4 ^ ((rb >> 1) & 3)) * 8;
  }

  f32x4 acc[4][4];
#pragma unroll
  for (int mi = 0; mi < 4; ++mi)
#pragma unroll
    for (int ni = 0; ni < 4; ++ni) acc[mi][ni] = 0.f;

  const int NK = DF / 32;
  for (int ks = 0; ks < NK; ++ks) {
    __syncthreads();
    gload16(pa0, As + lda0); gload16(pa1, As + lda1);
    gload16(pb0, Bs + lda0); gload16(pb1, Bs + lda1);
    pa0 += 32; pa1 += 32; pb0 += 32; pb1 += 32;
    __syncthreads();

    short8 af[4], bf_[4];
#pragma unroll
    for (int i = 0; i < 4; ++i) {
      af[i]  = *(const short8*)&As[aoff[i]];
      bf_[i] = *(const short8*)&Bs[boff[i]];
    }
#pragma unroll
    for (int mi = 0; mi < 4; ++mi)
#pragma unroll
      for (int ni = 0; ni < 4; ++ni)
        acc[mi][ni] = __builtin_amdgcn_mfma_f32_16x16x32_bf16(af[mi], bf_[ni], acc[mi][ni], 0, 0, 0);
  }

#pragma unroll
  for (int mi = 0; mi < 4; ++mi) {
#pragma unroll
    for (int ni = 0; ni < 4; ++ni) {
      int gn = nt * 128 + wn * 64 + ni * 16 + l15;
      float bias = b2[e * DM + gn];
      int rr = wm * 64 + mi * 16 + l4 * 4;
#pragma unroll
      for (int j = 0; j < 4; ++j) {
        int r = rr + j;
        float w = s_w[r];
        int tok = s_ts[r];
        if (tok >= NT) tok = 0;          // dummy row: w=0 -> adds exact 0.0
        atomicAdd(out + (size_t)tok * DM + gn, w * (acc[mi][ni][j] + bias));
      }
    }
  }
}

extern "C" void kernel_launch(void* const* d_in, const int* in_sizes, int n_in,
                              void* d_out, int out_size, void* d_ws, size_t ws_size,
                              hipStream_t stream) {
  const float* x  = (const float*)d_in[0];
  const float* Wg = (const float*)d_in[1];
  const float* W1 = (const float*)d_in[2];
  const float* b1 = (const float*)d_in[3];
  const float* W2 = (const float*)d_in[4];
  const float* b2 = (const float*)d_in[5];
  float* out = (float*)d_out;

  char* ws = (char*)d_ws;
  size_t o = 0;
  auto take = [&](size_t sz) { size_t p = o; o = (o + sz + 1023) & ~(size_t)1023; return p; };

  int*   meta = (int*)(ws + take(1024));
  int*   te   = (int*)(ws + take((size_t)NT * 2 * 4));
  float* tw   = (float*)(ws + take((size_t)NT * 2 * 4));
  int*   lt   = (int*)(ws + take((size_t)NE * NT * 4));
  float* lw   = (float*)(ws + take((size_t)NE * NT * 4));
  u16*   xbf  = (u16*)(ws + take((size_t)(NT + 1) * DM * 2));   // +1 dummy row
  u16*   W1T  = (u16*)(ws + take((size_t)NE * DM * DF * 2));
  u16*   H    = (u16*)(ws + take((size_t)HROWS * DF * 2));
  size_t needB = o;
  size_t needA = needB + ((size_t)NE * DM * DF * 2 + 1024);

  bool pathA = (ws_size >= needA);
  u16* W2T;
  if (pathA) {
    W2T = (u16*)(ws + take((size_t)NE * DM * DF * 2));
  } else {
    W2T = W1T;   // alias: converted between ffn1 and ffn2
  }

  hipMemsetAsync(meta, 0, 1024, stream);
  hipMemsetAsync(out, 0, (size_t)NT * DM * 4, stream);

  gate_k<<<NT / 4, 256, 0, stream>>>(x, Wg, te, tw, xbf);
  route_k<<<(NT * 2) / 256, 256, 0, stream>>>(te, tw, meta, lt, lw);
  finalize_k<<<1, 256, 0, stream>>>(meta, lt, lw);

  if (pathA) {
    prep_both<<<16384, 256, 0, stream>>>(W1, W2, W1T, W2T);
  } else {
    prep_wT<<<dim3(DF / 64, DM / 64, NE), 256, 0, stream>>>(W1, W1T, DM, DF);
  }

  ffn1_k<<<(DF / 128) * TIT, 256, 0, stream>>>(xbf, W1T, b1, lt, meta, H);

  if (!pathA)
    prep_wT<<<dim3(DM / 64, DF / 64, NE), 256, 0, stream>>>(W2, W2T, DF, DM);

  ffn2_k<<<(DM / 128) * TIT, 256, 0, stream>>>(H, W2T, b2, lt, lw, meta, out);
}

// Round 15
// 352.181 us; speedup vs baseline: 2.1848x; 1.0763x over previous
//
#include <hip/hip_runtime.h>
#include <math.h>

typedef __attribute__((ext_vector_type(8))) short short8;
typedef __attribute__((ext_vector_type(4))) float f32x4;
typedef unsigned short u16;

#define NT 4096      // tokens (B*S)
#define DM 1024      // d_model
#define DF 4096      // d_ff
#define NE 8         // experts
#define HROWS 9216   // max padded rows: 8192 + 8*128
#define TIT 72       // max m-tiles total
#define YROWS (2 * NT + 8)

static __device__ __forceinline__ u16 f2bf(float f) {
  union { float f; unsigned u; } v; v.f = f;
  return (u16)((v.u + 0x7fffu + ((v.u >> 16) & 1u)) >> 16);  // RNE
}

// branch-free tanh-form GELU: gelu(x) = x - x / (2^z + 1), z = k1*x + k2*x^3
static __device__ __forceinline__ float fast_gelu(float x) {
  float x2 = x * x;
  float z = x * __builtin_fmaf(x2, 0.1029392294f, 2.302118131f);
  float e, r;
  asm("v_exp_f32 %0, %1" : "=v"(e) : "v"(z));        // e = 2^z
  float e1 = e + 1.0f;
  asm("v_rcp_f32 %0, %1" : "=v"(r) : "v"(e1));       // r = 1/(e+1); e=inf -> 0
  return __builtin_fmaf(-x, r, x);
}

static __device__ __forceinline__ void gload16(const void* g, void* l) {
  __builtin_amdgcn_global_load_lds((const __attribute__((address_space(1))) void*)g,
                                   (__attribute__((address_space(3))) void*)l, 16, 0, 0);
}

// chunked XCD swizzle: nwg % 8 == 0. consecutive vids land on one XCD.
static __device__ __forceinline__ int xcd_swz(int bid, int nwg) {
  int per = nwg >> 3;
  return (bid & 7) * per + (bid >> 3);
}

// ---------------- gating + x->bf16 convert: one wave per token ----------------
__global__ __launch_bounds__(256) void gate_k(const float* __restrict__ x,
                                              const float* __restrict__ Wg,
                                              int* __restrict__ te,
                                              float* __restrict__ tw,
                                              u16* __restrict__ xbf) {
  int t = blockIdx.x * 4 + (threadIdx.x >> 6);
  int l = threadIdx.x & 63;
  float a0=0,a1=0,a2=0,a3=0,a4=0,a5=0,a6=0,a7=0;
  const float* xr = x + (size_t)t * DM;
  for (int k = l; k < DM; k += 64) {
    float xv = xr[k];
    const float4* wp = (const float4*)(Wg + k * 8);
    float4 w0 = wp[0], w1 = wp[1];
    a0 += xv * w0.x; a1 += xv * w0.y; a2 += xv * w0.z; a3 += xv * w0.w;
    a4 += xv * w1.x; a5 += xv * w1.y; a6 += xv * w1.z; a7 += xv * w1.w;
  }
  u16* xo = xbf + (size_t)t * DM;
#pragma unroll
  for (int h = 0; h < 2; ++h) {
    int k = h * 512 + l * 8;
    float4 a = *(const float4*)(xr + k);
    float4 b = *(const float4*)(xr + k + 4);
    short8 o8 = { (short)f2bf(a.x), (short)f2bf(a.y), (short)f2bf(a.z), (short)f2bf(a.w),
                  (short)f2bf(b.x), (short)f2bf(b.y), (short)f2bf(b.z), (short)f2bf(b.w) };
    *(short8*)(xo + k) = o8;
  }
#pragma unroll
  for (int s = 32; s >= 1; s >>= 1) {
    a0 += __shfl_down(a0, s); a1 += __shfl_down(a1, s);
    a2 += __shfl_down(a2, s); a3 += __shfl_down(a3, s);
    a4 += __shfl_down(a4, s); a5 += __shfl_down(a5, s);
    a6 += __shfl_down(a6, s); a7 += __shfl_down(a7, s);
  }
  if (l == 0) {
    float lg[8] = {a0,a1,a2,a3,a4,a5,a6,a7};
    float m = lg[0];
#pragma unroll
    for (int e = 1; e < 8; ++e) m = fmaxf(m, lg[e]);
    float p[8], s = 0.f;
#pragma unroll
    for (int e = 0; e < 8; ++e) { p[e] = expf(lg[e] - m); s += p[e]; }
#pragma unroll
    for (int e = 0; e < 8; ++e) p[e] /= s;
    int i0 = 0; float v0 = p[0];
#pragma unroll
    for (int e = 1; e < 8; ++e) if (p[e] > v0) { v0 = p[e]; i0 = e; }
    int i1 = -1; float v1 = -1.f;
#pragma unroll
    for (int e = 0; e < 8; ++e) {
      if (e == i0) continue;
      if (p[e] > v1) { v1 = p[e]; i1 = e; }
    }
    float norm = v0 + v1 + 1e-8f;
    te[t*2]   = i0; te[t*2+1] = i1;
    tw[t*2]   = v0 / norm; tw[t*2+1] = v1 / norm;
  }
}

// ---------------- routing ----------------
__global__ __launch_bounds__(256) void route_k(const int* __restrict__ te,
                                               const float* __restrict__ tw,
                                               int* __restrict__ meta,
                                               int* __restrict__ lt,
                                               float* __restrict__ lw) {
  int i = blockIdx.x * 256 + threadIdx.x;
  if (i >= NT * 2) return;
  int e = te[i];
  float w = tw[i];
  int pos = atomicAdd(&meta[e], 1);
  lt[e * NT + pos] = i;        // fused token*2 + slot
  lw[e * NT + pos] = w;
}

// meta: [0:8) cnt | [8:16) padded cnt | [16:24) row base | [24] ntiles | [32..) tile table
__global__ __launch_bounds__(256) void finalize_k(int* __restrict__ meta,
                                                  int* __restrict__ lt,
                                                  float* __restrict__ lw) {
  __shared__ int s_cnt[8], s_pc[8];
  if (threadIdx.x == 0) {
    int base = 0, nt_ = 0;
    for (int e = 0; e < 8; ++e) {
      int c = meta[e];
      int pc = (c + 127) & ~127;
      s_cnt[e] = c; s_pc[e] = pc;
      meta[8 + e] = pc;
      meta[16 + e] = base;
      base += pc;
      for (int mt = 0; mt < pc / 128; ++mt) meta[32 + nt_++] = (e << 16) | mt;
    }
    meta[24] = nt_;
  }
  __syncthreads();
  for (int e = 0; e < 8; ++e) {
    int c = s_cnt[e], pc = s_pc[e];
    for (int i = c + (int)threadIdx.x; i < pc; i += 256) {
      lt[e * NT + i] = 2 * NT;   // dummy -> trash Y row; ffn1 clamps gather
      lw[e * NT + i] = 0.f;
    }
  }
}

// ---------------- prepass body: one 64x64 tile  [K][N] fp32 -> [N][K] bf16 ----------------
static __device__ __forceinline__ void prep_tile(const float* __restrict__ ie,
                                                 u16* __restrict__ oe,
                                                 int K, int N, int k0, int n0) {
  __shared__ u16 t[64 * 72];
  const int tid = threadIdx.x;
  const int kr = tid >> 4, nq = (tid & 15) * 4;
#pragma unroll
  for (int it = 0; it < 4; ++it) {
    int k = it * 16 + kr;
    float4 v = *(const float4*)(ie + (size_t)(k0 + k) * N + n0 + nq);
    t[(nq + 0) * 72 + k] = f2bf(v.x);
    t[(nq + 1) * 72 + k] = f2bf(v.y);
    t[(nq + 2) * 72 + k] = f2bf(v.z);
    t[(nq + 3) * 72 + k] = f2bf(v.w);
  }
  __syncthreads();
#pragma unroll
  for (int it = 0; it < 2; ++it) {
    int idx = it * 256 + tid;
    int n = idx >> 3, kc = idx & 7;
    short8 v = *(const short8*)&t[n * 72 + kc * 8];
    *(short8*)(oe + (size_t)(n0 + n) * K + k0 + kc * 8) = v;
  }
}

// standalone (fallback path): W [E][K][N] fp32 -> [E][N][K] bf16
__global__ __launch_bounds__(256) void prep_wT(const float* __restrict__ in,
                                               u16* __restrict__ out, int K, int N) {
  const int e = blockIdx.z;
  prep_tile(in + (size_t)e * K * N, out + (size_t)e * K * N,
            K, N, blockIdx.y * 64, blockIdx.x * 64);
}

// merged: W1 and W2 in one launch (8192 + 8192 tile-blocks)
__global__ __launch_bounds__(256) void prep_both(const float* __restrict__ W1,
                                                 const float* __restrict__ W2,
                                                 u16* __restrict__ W1T,
                                                 u16* __restrict__ W2T) {
  int bid = blockIdx.x;
  if (bid < 8192) {
    int e = bid >> 10, rem = bid & 1023;           // 64 ntiles x 16 ktiles
    prep_tile(W1 + (size_t)e * DM * DF, W1T + (size_t)e * DM * DF,
              DM, DF, (rem >> 6) * 64, (rem & 63) * 64);
  } else {
    bid -= 8192;
    int e = bid >> 10, rem = bid & 1023;           // 16 ntiles x 64 ktiles
    prep_tile(W2 + (size_t)e * DF * DM, W2T + (size_t)e * DF * DM,
              DF, DM, (rem >> 4) * 64, (rem & 15) * 64);
  }
}

// ---------------- FFN1: H = gelu(Xg @ W1 + b1), R6 loop ----------------
__global__ __launch_bounds__(256) void ffn1_k(const u16* __restrict__ xbf,
                                              const u16* __restrict__ W1T,
                                              const float* __restrict__ b1,
                                              const int* __restrict__ lt,
                                              const int* __restrict__ meta,
                                              u16* __restrict__ H) {
  const int vid = xcd_swz(blockIdx.x, (DF / 128) * TIT);
  const int nt = vid & 31;            // DF/128
  const int ti = vid >> 5;            // tile-table index
  if (ti >= meta[24]) return;
  const int em = meta[32 + ti];
  const int e = em >> 16, mt = em & 0xffff;
  const int rbase = meta[16 + e];

  __shared__ u16 As[128 * 32];
  __shared__ u16 Bs[128 * 32];

  const int tid = threadIdx.x, lane = tid & 63, wv = tid >> 6;
  const int wm = wv >> 1, wn = wv & 1, l15 = lane & 15, l4 = lane >> 4;

  int r0i = tid >> 2, s0 = tid & 3;
  int r1i = (256 + tid) >> 2;
  int kg0 = s0 ^ ((r0i >> 1) & 3);
  int kg1 = s0 ^ ((r1i >> 1) & 3);
  int tok0 = lt[e * NT + mt * 128 + r0i] >> 1; if (tok0 >= NT) tok0 = 0;
  int tok1 = lt[e * NT + mt * 128 + r1i] >> 1; if (tok1 >= NT) tok1 = 0;
  const u16* pa0 = xbf + (size_t)tok0 * DM + kg0 * 8;
  const u16* pa1 = xbf + (size_t)tok1 * DM + kg1 * 8;
  const u16* pb0 = W1T + ((size_t)e * DF + nt * 128 + r0i) * DM + kg0 * 8;
  const u16* pb1 = W1T + ((size_t)e * DF + nt * 128 + r1i) * DM + kg1 * 8;
  const int lda0 = (wv * 64) * 8, lda1 = (256 + wv * 64) * 8;

  int aoff[4], boff[4];
#pragma unroll
  for (int i = 0; i < 4; ++i) {
    int ra = wm * 64 + i * 16 + l15;
    aoff[i] = ra * 32 + (l4 ^ ((ra >> 1) & 3)) * 8;
    int rb = wn * 64 + i * 16 + l15;
    boff[i] = rb * 32 + (l4 ^ ((rb >> 1) & 3)) * 8;
  }

  f32x4 acc[4][4];
#pragma unroll
  for (int mi = 0; mi < 4; ++mi)
#pragma unroll
    for (int ni = 0; ni < 4; ++ni) acc[mi][ni] = 0.f;

  const int NK = DM / 32;
  for (int ks = 0; ks < NK; ++ks) {
    __syncthreads();
    gload16(pa0, As + lda0); gload16(pa1, As + lda1);
    gload16(pb0, Bs + lda0); gload16(pb1, Bs + lda1);
    pa0 += 32; pa1 += 32; pb0 += 32; pb1 += 32;
    __syncthreads();

    short8 af[4], bf_[4];
#pragma unroll
    for (int i = 0; i < 4; ++i) {
      af[i]  = *(const short8*)&As[aoff[i]];
      bf_[i] = *(const short8*)&Bs[boff[i]];
    }
#pragma unroll
    for (int mi = 0; mi < 4; ++mi)
#pragma unroll
      for (int ni = 0; ni < 4; ++ni)
        acc[mi][ni] = __builtin_amdgcn_mfma_f32_16x16x32_bf16(af[mi], bf_[ni], acc[mi][ni], 0, 0, 0);
  }

  const size_t hrow0 = (size_t)rbase + mt * 128;
#pragma unroll
  for (int mi = 0; mi < 4; ++mi) {
#pragma unroll
    for (int ni = 0; ni < 4; ++ni) {
      int gn = nt * 128 + wn * 64 + ni * 16 + l15;
      float bias = b1[e * DF + gn];
      int rr = wm * 64 + mi * 16 + l4 * 4;
#pragma unroll
      for (int j = 0; j < 4; ++j) {
        float v = fast_gelu(acc[mi][ni][j] + bias);
        H[(hrow0 + rr + j) * DF + gn] = f2bf(v);
      }
    }
  }
}

// ---------------- FFN2: R6 loop; per-slot Y or atomic ----------------
template <bool USEY>
__global__ __launch_bounds__(256) void ffn2_k(const u16* __restrict__ H,
                                              const u16* __restrict__ W2T,
                                              const float* __restrict__ b2,
                                              const int* __restrict__ lt,
                                              const float* __restrict__ lw,
                                              const int* __restrict__ meta,
                                              float* __restrict__ Y,
                                              float* __restrict__ out) {
  const int vid = xcd_swz(blockIdx.x, (DM / 128) * TIT);
  const int nt = vid & 7;             // DM/128
  const int ti = vid >> 3;
  if (ti >= meta[24]) return;
  const int em = meta[32 + ti];
  const int e = em >> 16, mt = em & 0xffff;
  const int rbase = meta[16 + e];

  __shared__ u16 As[128 * 32];
  __shared__ u16 Bs[128 * 32];
  __shared__ int s_ts[128];
  __shared__ float s_w[128];

  const int tid = threadIdx.x, lane = tid & 63, wv = tid >> 6;
  const int wm = wv >> 1, wn = wv & 1, l15 = lane & 15, l4 = lane >> 4;

  if (tid < 128) {
    s_ts[tid] = lt[e * NT + mt * 128 + tid];
    s_w[tid]  = lw[e * NT + mt * 128 + tid];
  }

  int r0i = tid >> 2, s0 = tid & 3;
  int r1i = (256 + tid) >> 2;
  int kg0 = s0 ^ ((r0i >> 1) & 3);
  int kg1 = s0 ^ ((r1i >> 1) & 3);
  const u16* pa0 = H + ((size_t)rbase + mt * 128 + r0i) * DF + kg0 * 8;
  const u16* pa1 = H + ((size_t)rbase + mt * 128 + r1i) * DF + kg1 * 8;
  const u16* pb0 = W2T + ((size_t)e * DM + nt * 128 + r0i) * DF + kg0 * 8;
  const u16* pb1 = W2T + ((size_t)e * DM + nt * 128 + r1i) * DF + kg1 * 8;
  const int lda0 = (wv * 64) * 8, lda1 = (256 + wv * 64) * 8;

  int aoff[4], boff[4];
#pragma unroll
  for (int i = 0; i < 4; ++i) {
    int ra = wm * 64 + i * 16 + l15;
    aoff[i] = ra * 32 + (l4 ^ ((ra >> 1) & 3)) * 8;
    int rb = wn * 64 + i * 16 + l15;
    boff[i] = rb * 32 + (l4 ^ ((rb >> 1) & 3)) * 8;
  }

  f32x4 acc[4][4];
#pragma unroll
  for (int mi = 0; mi < 4; ++mi)
#pragma unroll
    for (int ni = 0; ni < 4; ++ni) acc[mi][ni] = 0.f;

  const int NK = DF / 32;
  for (int ks = 0; ks < NK; ++ks) {
    __syncthreads();
    gload16(pa0, As + lda0); gload16(pa1, As + lda1);
    gload16(pb0, Bs + lda0); gload16(pb1, Bs + lda1);
    pa0 += 32; pa1 += 32; pb0 += 32; pb1 += 32;
    __syncthreads();

    short8 af[4], bf_[4];
#pragma unroll
    for (int i = 0; i < 4; ++i) {
      af[i]  = *(const short8*)&As[aoff[i]];
      bf_[i] = *(const short8*)&Bs[boff[i]];
    }
#pragma unroll
    for (int mi = 0; mi < 4; ++mi)
#pragma unroll
      for (int ni = 0; ni < 4; ++ni)
        acc[mi][ni] = __builtin_amdgcn_mfma_f32_16x16x32_bf16(af[mi], bf_[ni], acc[mi][ni], 0, 0, 0);
  }

#pragma unroll
  for (int mi = 0; mi < 4; ++mi) {
#pragma unroll
    for (int ni = 0; ni < 4; ++ni) {
      int gn = nt * 128 + wn * 64 + ni * 16 + l15;
      float bias = b2[e * DM + gn];
      int rr = wm * 64 + mi * 16 + l4 * 4;
#pragma unroll
      for (int j = 0; j < 4; ++j) {
        int r = rr + j;
        float w = s_w[r];
        int ts = s_ts[r];
        float v = w * (acc[mi][ni][j] + bias);
        if (USEY) {
          Y[(size_t)ts * DM + gn] = v;
        } else {
          int tok = ts >> 1;
          if (tok >= NT) tok = 0;
          atomicAdd(out + (size_t)tok * DM + gn, v);
        }
      }
    }
  }
}

// ---------------- combine: out[t] = Y[2t] + Y[2t+1] ----------------
__global__ __launch_bounds__(256) void combine_k(const float* __restrict__ Y,
                                                 float* __restrict__ out) {
  size_t i4 = (size_t)blockIdx.x * 256 + threadIdx.x;
  size_t t = i4 >> 8;
  int c4 = (int)(i4 & 255) * 4;
  const float4 a = *(const float4*)(Y + (2 * t) * DM + c4);
  const float4 b = *(const float4*)(Y + (2 * t + 1) * DM + c4);
  float4 o = { a.x + b.x, a.y + b.y, a.z + b.z, a.w + b.w };
  *(float4*)(out + t * DM + c4) = o;
}

extern "C" void kernel_launch(void* const* d_in, const int* in_sizes, int n_in,
                              void* d_out, int out_size, void* d_ws, size_t ws_size,
                              hipStream_t stream) {
  const float* x  = (const float*)d_in[0];
  const float* Wg = (const float*)d_in[1];
  const float* W1 = (const float*)d_in[2];
  const float* b1 = (const float*)d_in[3];
  const float* W2 = (const float*)d_in[4];
  const float* b2 = (const float*)d_in[5];
  float* out = (float*)d_out;

  char* ws = (char*)d_ws;
  size_t o = 0;
  auto take = [&](size_t sz) { size_t p = o; o = (o + sz + 1023) & ~(size_t)1023; return p; };

  int*   meta = (int*)(ws + take(1024));
  int*   te   = (int*)(ws + take((size_t)NT * 2 * 4));
  float* tw   = (float*)(ws + take((size_t)NT * 2 * 4));
  int*   lt   = (int*)(ws + take((size_t)NE * NT * 4));
  float* lw   = (float*)(ws + take((size_t)NE * NT * 4));
  u16*   xbf  = (u16*)(ws + take((size_t)NT * DM * 2));
  u16*   W1T  = (u16*)(ws + take((size_t)NE * DM * DF * 2));
  u16*   H    = (u16*)(ws + take((size_t)HROWS * DF * 2));
  size_t needB = o;
  size_t ySz = (size_t)YROWS * DM * 4;
  size_t needA = needB + ((size_t)NE * DM * DF * 2 + 1024) + (ySz + 1024);

  bool pathA = (ws_size >= needA);
  u16*   W2T;
  float* Y = nullptr;
  if (pathA) {
    W2T = (u16*)(ws + take((size_t)NE * DM * DF * 2));
    Y   = (float*)(ws + take(ySz));
  } else {
    W2T = W1T;   // alias: converted between ffn1 and ffn2
  }

  hipMemsetAsync(meta, 0, 1024, stream);
  if (!pathA) hipMemsetAsync(out, 0, (size_t)NT * DM * 4, stream);

  gate_k<<<NT / 4, 256, 0, stream>>>(x, Wg, te, tw, xbf);
  route_k<<<(NT * 2) / 256, 256, 0, stream>>>(te, tw, meta, lt, lw);
  finalize_k<<<1, 256, 0, stream>>>(meta, lt, lw);

  if (pathA) {
    prep_both<<<16384, 256, 0, stream>>>(W1, W2, W1T, W2T);
  } else {
    prep_wT<<<dim3(DF / 64, DM / 64, NE), 256, 0, stream>>>(W1, W1T, DM, DF);
  }

  ffn1_k<<<(DF / 128) * TIT, 256, 0, stream>>>(xbf, W1T, b1, lt, meta, H);

  if (!pathA)
    prep_wT<<<dim3(DM / 64, DF / 64, NE), 256, 0, stream>>>(W2, W2T, DF, DM);

  if (pathA) {
    ffn2_k<true><<<(DM / 128) * TIT, 256, 0, stream>>>(H, W2T, b2, lt, lw, meta, Y, out);
    combine_k<<<NT, 256, 0, stream>>>(Y, out);
  } else {
    ffn2_k<false><<<(DM / 128) * TIT, 256, 0, stream>>>(H, W2T, b2, lt, lw, meta, Y, out);
  }
}